// Round 8
// baseline (505.728 us; speedup 1.0000x reference)
//
#include <hip/hip_runtime.h>
#include <hip/hip_bf16.h>

#define DEVI __device__ __forceinline__

typedef __attribute__((ext_vector_type(4))) float f32x4;
typedef __attribute__((ext_vector_type(8))) short bf16x8;
typedef __attribute__((ext_vector_type(4))) unsigned int u32x4;

typedef __attribute__((address_space(3))) unsigned int lds_u32_t;
typedef __attribute__((address_space(1))) unsigned int glb_u32_t;

// ---------- constants ----------
constexpr int KTOT  = 66048;          // 65536 main + 256 inp1-linear + 256 inp2-linear
// workspace offsets (bytes)
constexpr size_t OFF_WPT  = 0;                      // Wp_t bf16 [256][66048]  = 33,816,576
constexpr size_t OFF_W2BT = 33816576;               // W2^T bf16 [256][256]    = 131,072
constexpr size_t OFF_B1P  = OFF_W2BT + 131072;      // b1 + W1[66048,:] f32    = 1,024
constexpr size_t OFF_HF   = OFF_B1P + 1024;         // h fp32 [4096][256]      = 4,194,304
constexpr size_t OFF_HB   = OFF_HF + 4194304;       // h bf16 [4096][256]      = 2,097,152

// ---------- bf16 helpers: scalar casts -> compiler emits v_cvt_pk_bf16_f32 ----------
DEVI unsigned short f2bf(float x) {
  __hip_bfloat16 h = __float2bfloat16(x);
  return *reinterpret_cast<unsigned short*>(&h);
}
DEVI unsigned int pack2(float a, float b) {
  return (unsigned int)f2bf(a) | ((unsigned int)f2bf(b) << 16);
}

// =====================================================================
// K0: repack W1 (f32 [66049][256]) -> Wp_t (bf16 [256 n][66048 k'])
// =====================================================================
__global__ __launch_bounds__(256) void k_repack(const float* __restrict__ W1,
                                                unsigned short* __restrict__ wpt) {
  __shared__ float tile[64][65];
  int kt = blockIdx.x, nt = blockIdx.y, t = threadIdx.x;
  {
    int r = t >> 2, c4 = (t & 3) * 16;
    int kp = kt * 64 + r;
    int src;
    if (kp < 65536)      src = (kp >> 8) * 257 + (kp & 255);
    else if (kp < 65792) src = (kp - 65536) * 257 + 256;
    else                 src = kp;
    const float* rp = W1 + (size_t)src * 256 + nt * 64 + c4;
#pragma unroll
    for (int q = 0; q < 4; ++q) {
      f32x4 x = *(const f32x4*)(rp + q * 4);
#pragma unroll
      for (int e = 0; e < 4; ++e) tile[r][c4 + q * 4 + e] = x[e];
    }
  }
  __syncthreads();
  {
    int nl = t >> 2, kk = (t & 3) * 16;
    int n = nt * 64 + nl;
    u32x4 lo, hi;
#pragma unroll
    for (int m = 0; m < 4; ++m)
      lo[m] = pack2(tile[kk + 2 * m][nl], tile[kk + 2 * m + 1][nl]);
#pragma unroll
    for (int m = 0; m < 4; ++m)
      hi[m] = pack2(tile[kk + 8 + 2 * m][nl], tile[kk + 9 + 2 * m][nl]);
    unsigned short* dst = wpt + (size_t)n * KTOT + kt * 64 + kk;
    *(u32x4*)dst = lo;
    *(u32x4*)(dst + 8) = hi;
  }
}

// =====================================================================
// K1: zero h_f32; W2 -> W2^T bf16; b1p = b1 + W1[66048,:]
// =====================================================================
__global__ __launch_bounds__(256) void k_misc(const float* __restrict__ W1,
                                              const float* __restrict__ b1,
                                              const float* __restrict__ W2,
                                              float* __restrict__ hf,
                                              unsigned short* __restrict__ w2bt,
                                              float* __restrict__ b1p) {
  int idx = blockIdx.x * 256 + threadIdx.x;
  hf[idx] = 0.f;
  if (idx < 65536) {
    int n2 = idx >> 8, n = idx & 255;
    w2bt[idx] = f2bf(W2[n * 256 + n2]);
  }
  if (idx < 256) b1p[idx] = b1[idx] + W1[(size_t)66048 * 256 + idx];
}

// =====================================================================
// K2: 8-phase m201-style pipeline. BM=256,BN=256,BK=64, 8 waves (2x4),
//     wave tile 128x64, LDS 128K dbuf {A 32K | W 32K} x2, 1 blk/CU.
//     Per tile, 4 phases: reads+stage/build | bar | lgkm0 | prio MFMA | bar.
//     W: global_load_lds 2 phases ahead; A: VALU-built (wave-split ph2/ph3).
//     LDS swizzle: unit u ^ (row&7) on reads/writes/stage-source.
// =====================================================================
__global__ __launch_bounds__(512, 2) void k_main(const float* __restrict__ inp1,
                                                 const float* __restrict__ inp2,
                                                 const unsigned short* __restrict__ wpt,
                                                 float* __restrict__ hf) {
  __shared__ char smem[131072];   // [buf0: A@0 W@32K][buf1: A@64K W@96K]

  const int lin = blockIdx.x;             // 0..255
  const int xcd = lin & 7, slot = lin >> 3;
  const int c = xcd + ((slot >> 4) << 3); // i-chunk 0..15, XCD-pinned
  const int b0 = (slot & 15) * 256;
  const int i0 = c * 16;

  const int t = threadIdx.x;
  const int lane = t & 63, wid = t >> 6;
  const int wrow = wid >> 2, wcol = wid & 3;      // 2 x 4 waves, 128 x 64 tile
  const int r16 = lane & 15, kq = lane >> 4;

  // builder: thread -> one row, 4 units
  const int brow_l = t >> 1;                      // 0..255
  const int bu0 = (t & 1) * 4;
  const int brow7 = brow_l & 7;
  const int a_wbase = brow_l * 128;
  const bool bhalf0 = (brow_l < 128);             // builds at ph2 (waves 0-3) else ph3
  const float* inp1_row = inp1 + (size_t)(b0 + brow_l) * 256;
  const float* inp2_row = inp2 + (size_t)(b0 + brow_l) * 256;

  // W stage invariants: q=0,1 -> g = wid*128 + q*64 + lane
  const unsigned short* wsrc[2];
  int wdst[2];
#pragma unroll
  for (int q = 0; q < 2; ++q) {
    int g = wid * 128 + q * 64 + lane;
    int nl = g >> 3, up = g & 7, u = up ^ (nl & 7);
    wsrc[q] = wpt + (size_t)nl * KTOT + u * 8;    // + h*128*KTOT + k0 at call
    wdst[q] = g * 16;                              // + h*16384 within W region
  }

  auto stageW = [&](char* Wreg, int h, int k0) {
#pragma unroll
    for (int q = 0; q < 2; ++q)
      __builtin_amdgcn_global_load_lds(
          (const glb_u32_t*)(wsrc[q] + (size_t)h * 128 * KTOT + k0),
          (lds_u32_t*)(Wreg + h * 16384 + wdst[q]), 16, 0, 0);
  };

  float v2[32];                                    // row's inp2 slice for jw window
  auto loadv2 = [&](int jw) {
    const float* p = inp2_row + jw * 64 + bu0 * 8;
#pragma unroll
    for (int q8 = 0; q8 < 8; ++q8) {
      f32x4 x = *(const f32x4*)(p + q8 * 4);
#pragma unroll
      for (int e = 0; e < 4; ++e) v2[q8 * 4 + e] = x[e];
    }
  };

  auto buildA = [&](char* Areg, int ii) {
    float s = inp1_row[i0 + ii];
#pragma unroll
    for (int uu = 0; uu < 4; ++uu) {
      int u = bu0 + uu;
      u32x4 pk;
#pragma unroll
      for (int m = 0; m < 4; ++m)
        pk[m] = pack2(v2[uu * 8 + 2 * m] * s, v2[uu * 8 + 2 * m + 1] * s);
      *(u32x4*)(Areg + a_wbase + ((u ^ brow7) << 4)) = pk;
    }
  };

  auto buildTail = [&](char* Areg) {
    const float* srcp = (c < 12) ? (inp1_row + (c - 8) * 64) : (inp2_row + (c - 12) * 64);
#pragma unroll
    for (int uu = 0; uu < 4; ++uu) {
      int u = bu0 + uu;
      f32x4 x0 = *(const f32x4*)(srcp + u * 8);
      f32x4 x1 = *(const f32x4*)(srcp + u * 8 + 4);
      u32x4 pk;
      pk[0] = pack2(x0[0], x0[1]); pk[1] = pack2(x0[2], x0[3]);
      pk[2] = pack2(x1[0], x1[1]); pk[3] = pack2(x1[2], x1[3]);
      *(u32x4*)(Areg + a_wbase + ((u ^ brow7) << 4)) = pk;
    }
  };

  f32x4 acc[8][4] = {};
  bf16x8 af[4][2];       // A frags for current rg-half (reused across 2 phases)
  bf16x8 bfr[2][2];      // B frags for current cg-pair

  auto readA = [&](const char* Areg, int rgh) {
#pragma unroll
    for (int r = 0; r < 4; ++r) {
      int row = wrow * 128 + (rgh * 4 + r) * 16 + r16;
      int rb = row * 128, r7 = row & 7;
#pragma unroll
      for (int ks = 0; ks < 2; ++ks)
        af[r][ks] = *(const bf16x8*)(Areg + rb + (((ks * 4 + kq) ^ r7) << 4));
    }
  };
  auto readB = [&](const char* Wreg, int cgp) {
#pragma unroll
    for (int cl = 0; cl < 2; ++cl) {
      int n = wcol * 64 + (cgp * 2 + cl) * 16 + r16;
      int nb = n * 128, n7 = n & 7;
#pragma unroll
      for (int ks = 0; ks < 2; ++ks)
        bfr[cl][ks] = *(const bf16x8*)(Wreg + nb + (((ks * 4 + kq) ^ n7) << 4));
    }
  };

#define MFMA_Q(rgh, cgp)                                                        \
  do {                                                                          \
    __builtin_amdgcn_s_setprio(1);                                              \
    _Pragma("unroll") for (int ks = 0; ks < 2; ++ks)                            \
      _Pragma("unroll") for (int r = 0; r < 4; ++r)                             \
        _Pragma("unroll") for (int cl = 0; cl < 2; ++cl)                        \
          acc[(rgh)*4 + r][(cgp)*2 + cl] = __builtin_amdgcn_mfma_f32_16x16x32_bf16( \
              af[r][ks], bfr[cl][ks], acc[(rgh)*4 + r][(cgp)*2 + cl], 0, 0, 0); \
    __builtin_amdgcn_s_setprio(0);                                              \
  } while (0)

#define PHASE_SYNC()                                            \
  do {                                                          \
    asm volatile("" ::: "memory");                              \
    __builtin_amdgcn_s_barrier();                               \
    asm volatile("s_waitcnt lgkmcnt(0)" ::: "memory");          \
    __builtin_amdgcn_sched_barrier(0);                          \
  } while (0)

#define PHASE_END()                                             \
  do {                                                          \
    asm volatile("" ::: "memory");                              \
    __builtin_amdgcn_s_barrier();                               \
  } while (0)

  const int NT = 64 + (c >= 8 ? 1 : 0);

  // prologue: tile 0 -> buf0
  loadv2(0);
  stageW(smem + 32768, 0, i0 * 256);
  stageW(smem + 32768, 1, i0 * 256);
  buildA(smem, 0);
  asm volatile("s_waitcnt vmcnt(0) lgkmcnt(0)" ::: "memory");
  __syncthreads();

  for (int tt = 0; tt < NT; ++tt) {
    char* Acur = smem + (tt & 1) * 65536;
    char* Wcur = Acur + 32768;
    char* Anxt = smem + (((tt & 1) ^ 1)) * 65536;
    char* Wnxt = Anxt + 32768;
    const int sn = tt + 1;
    const bool hn = sn < NT;
    const bool tail_n = hn && (sn == 64);
    const int ii_n = sn & 15, jw_n = sn >> 4;
    const int k0n = tail_n ? (65536 + (c - 8) * 64)
                           : ((i0 + ii_n) * 256 + jw_n * 64);

    // ph0: A rg-half0 + B cg-pair0; stage W half0(next)
    readA(Acur, 0); readB(Wcur, 0);
    if (hn) stageW(Wnxt, 0, k0n);
    PHASE_SYNC(); MFMA_Q(0, 0); PHASE_END();

    // ph1: B cg-pair1 (A frags reused); stage W half1(next)
    readB(Wcur, 1);
    if (hn) stageW(Wnxt, 1, k0n);
    PHASE_SYNC(); MFMA_Q(0, 1); PHASE_END();

    // ph2: A rg-half1 + B cg-pair0; build A(next) rows 0-127 (waves 0-3)
    readA(Acur, 1); readB(Wcur, 0);
    if (hn && !tail_n && (sn & 15) == 0) loadv2(jw_n);
    if (hn && bhalf0) {
      if (!tail_n) buildA(Anxt, ii_n); else buildTail(Anxt);
    }
    PHASE_SYNC(); MFMA_Q(1, 0); PHASE_END();

    // ph3: B cg-pair1; build A(next) rows 128-255 (waves 4-7); drain W stages
    readB(Wcur, 1);
    if (hn && !bhalf0) {
      if (!tail_n) buildA(Anxt, ii_n); else buildTail(Anxt);
    }
    asm volatile("s_waitcnt vmcnt(0)" ::: "memory");
    PHASE_SYNC(); MFMA_Q(1, 1); PHASE_END();
  }

  // epilogue: fp32 atomic accumulate (split-K over 16 chunks)
#pragma unroll
  for (int rg = 0; rg < 8; ++rg)
#pragma unroll
    for (int cg = 0; cg < 4; ++cg) {
      int n = wcol * 64 + cg * 16 + r16;
      int br = b0 + wrow * 128 + rg * 16 + kq * 4;
#pragma unroll
      for (int r = 0; r < 4; ++r)
        atomicAdd(hf + (size_t)(br + r) * 256 + n, acc[rg][cg][r]);
    }
#undef MFMA_Q
#undef PHASE_SYNC
#undef PHASE_END
}

// =====================================================================
// K3: h = relu(hf + b1p) -> bf16
// =====================================================================
__global__ __launch_bounds__(256) void k_finalize(const float* __restrict__ hf,
                                                  const float* __restrict__ b1p,
                                                  unsigned short* __restrict__ hb) {
  int idx = blockIdx.x * 256 + threadIdx.x;
  float v = hf[idx] + b1p[idx & 255];
  hb[idx] = f2bf(v > 0.f ? v : 0.f);
}

// =====================================================================
// K4: out = relu(h @ W2 + b2)
// =====================================================================
__global__ __launch_bounds__(256) void k_gemm2(const unsigned short* __restrict__ hb,
                                               const unsigned short* __restrict__ w2bt,
                                               const float* __restrict__ b2,
                                               float* __restrict__ out) {
  int b0 = blockIdx.x * 128, n0 = blockIdx.y * 128;
  int t = threadIdx.x, lane = t & 63, w = t >> 6;
  int wr = w >> 1, wc = w & 1;
  int r16 = lane & 15, k8 = (lane >> 4) * 8;
  f32x4 acc[4][4] = {};
  for (int ks = 0; ks < 8; ++ks) {
    int k = ks * 32 + k8;
    bf16x8 a[4], bb[4];
#pragma unroll
    for (int rg = 0; rg < 4; ++rg) {
      int b_ = b0 + wr * 64 + rg * 16 + r16;
      a[rg] = *(const bf16x8*)(hb + (size_t)b_ * 256 + k);
    }
#pragma unroll
    for (int cg = 0; cg < 4; ++cg) {
      int n2 = n0 + wc * 64 + cg * 16 + r16;
      bb[cg] = *(const bf16x8*)(w2bt + (size_t)n2 * 256 + k);
    }
#pragma unroll
    for (int rg = 0; rg < 4; ++rg)
#pragma unroll
      for (int cg = 0; cg < 4; ++cg)
        acc[rg][cg] = __builtin_amdgcn_mfma_f32_16x16x32_bf16(a[rg], bb[cg], acc[rg][cg], 0, 0, 0);
  }
#pragma unroll
  for (int rg = 0; rg < 4; ++rg)
#pragma unroll
    for (int cg = 0; cg < 4; ++cg) {
      int n2 = n0 + wc * 64 + cg * 16 + r16;
      float bias = b2[n2];
      int brow = b0 + wr * 64 + rg * 16 + (lane >> 4) * 4;
#pragma unroll
      for (int r = 0; r < 4; ++r) {
        float val = acc[rg][cg][r] + bias;
        out[(size_t)(brow + r) * 256 + n2] = val > 0.f ? val : 0.f;
      }
    }
}

// =====================================================================
extern "C" void kernel_launch(void* const* d_in, const int* in_sizes, int n_in,
                              void* d_out, int out_size, void* d_ws, size_t ws_size,
                              hipStream_t stream) {
  const float* inp1 = (const float*)d_in[0];
  const float* inp2 = (const float*)d_in[1];
  const float* W1   = (const float*)d_in[2];
  const float* b1   = (const float*)d_in[3];
  const float* W2   = (const float*)d_in[4];
  const float* b2   = (const float*)d_in[5];
  float* out = (float*)d_out;

  char* ws = (char*)d_ws;
  unsigned short* wpt  = (unsigned short*)(ws + OFF_WPT);
  unsigned short* w2bt = (unsigned short*)(ws + OFF_W2BT);
  float* b1p = (float*)(ws + OFF_B1P);
  float* hf  = (float*)(ws + OFF_HF);
  unsigned short* hb = (unsigned short*)(ws + OFF_HB);

  k_repack<<<dim3(1032, 4), 256, 0, stream>>>(W1, wpt);
  k_misc<<<4096, 256, 0, stream>>>(W1, b1, W2, hf, w2bt, b1p);
  k_main<<<256, 512, 0, stream>>>(inp1, inp2, wpt, hf);
  k_finalize<<<4096, 256, 0, stream>>>(hf, b1p, hb);
  k_gemm2<<<dim3(32, 2), 256, 0, stream>>>(hb, w2bt, b2, out);
}

// Round 10
// 302.361 us; speedup vs baseline: 1.6726x; 1.6726x over previous
//
#include <hip/hip_runtime.h>
#include <hip/hip_bf16.h>

#define DEVI __device__ __forceinline__

typedef __attribute__((ext_vector_type(4))) float f32x4;
typedef __attribute__((ext_vector_type(8))) short bf16x8;
typedef __attribute__((ext_vector_type(4))) unsigned int u32x4;

typedef __attribute__((address_space(3))) unsigned int lds_u32_t;
typedef __attribute__((address_space(1))) unsigned int glb_u32_t;

// ---------- constants ----------
constexpr int KTOT  = 66048;          // 65536 main + 256 inp1-linear + 256 inp2-linear
// workspace offsets (bytes)
constexpr size_t OFF_WPT  = 0;                      // Wp_t bf16 [256][66048]  = 33,816,576
constexpr size_t OFF_W2BT = 33816576;               // W2^T bf16 [256][256]    = 131,072
constexpr size_t OFF_B1P  = OFF_W2BT + 131072;      // b1 + W1[66048,:] f32    = 1,024
constexpr size_t OFF_HF   = OFF_B1P + 1024;         // h fp32 [4096][256]      = 4,194,304

// ---------- bf16 helpers: casts -> compiler emits v_cvt_pk_bf16_f32 ----------
DEVI unsigned short f2bf(float x) {
  __hip_bfloat16 h = __float2bfloat16(x);
  return *reinterpret_cast<unsigned short*>(&h);
}
DEVI unsigned int pack2(float a, float b) {
  return (unsigned int)f2bf(a) | ((unsigned int)f2bf(b) << 16);
}

// =====================================================================
// K0: repack W1 (f32 [66049][256]) -> Wp_t (bf16 [256 n][66048 k'])
// =====================================================================
__global__ __launch_bounds__(256) void k_repack(const float* __restrict__ W1,
                                                unsigned short* __restrict__ wpt) {
  __shared__ float tile[64][65];
  int kt = blockIdx.x, nt = blockIdx.y, t = threadIdx.x;
  {
    int r = t >> 2, c4 = (t & 3) * 16;
    int kp = kt * 64 + r;
    int src;
    if (kp < 65536)      src = (kp >> 8) * 257 + (kp & 255);
    else if (kp < 65792) src = (kp - 65536) * 257 + 256;
    else                 src = kp;
    const float* rp = W1 + (size_t)src * 256 + nt * 64 + c4;
#pragma unroll
    for (int q = 0; q < 4; ++q) {
      f32x4 x = *(const f32x4*)(rp + q * 4);
#pragma unroll
      for (int e = 0; e < 4; ++e) tile[r][c4 + q * 4 + e] = x[e];
    }
  }
  __syncthreads();
  {
    int nl = t >> 2, kk = (t & 3) * 16;
    int n = nt * 64 + nl;
    u32x4 lo, hi;
#pragma unroll
    for (int m = 0; m < 4; ++m)
      lo[m] = pack2(tile[kk + 2 * m][nl], tile[kk + 2 * m + 1][nl]);
#pragma unroll
    for (int m = 0; m < 4; ++m)
      hi[m] = pack2(tile[kk + 8 + 2 * m][nl], tile[kk + 9 + 2 * m][nl]);
    unsigned short* dst = wpt + (size_t)n * KTOT + kt * 64 + kk;
    *(u32x4*)dst = lo;
    *(u32x4*)(dst + 8) = hi;
  }
}

// =====================================================================
// K1: W2 -> W2^T bf16; b1p = b1 + W1[66048,:]   (hf zeroed by memsetAsync)
// =====================================================================
__global__ __launch_bounds__(256) void k_misc(const float* __restrict__ W1,
                                              const float* __restrict__ b1,
                                              const float* __restrict__ W2,
                                              unsigned short* __restrict__ w2bt,
                                              float* __restrict__ b1p) {
  int idx = blockIdx.x * 256 + threadIdx.x;       // 256 blocks -> 65536
  int n2 = idx >> 8, n = idx & 255;
  w2bt[idx] = f2bf(W2[n * 256 + n2]);
  if (idx < 256) b1p[idx] = b1[idx] + W1[(size_t)66048 * 256 + idx];
}

// =====================================================================
// K2: main bilinear GEMM — r5 skeleton (dbuf, BM=256,BN=256,BK=64, 8 waves
//     2x4, wave tile 128x64, 1 blk/CU) + cvt_pk pack. Sync = __syncthreads
//     (full drain; stage loads issued a full MFMA phase earlier -> cheap).
// =====================================================================
DEVI void mfma_tiles(const char* A_lds, const char* W_lds, f32x4 (&acc)[8][4],
                     int lane, int wr, int wc) {
  int r16 = lane & 15;
  int kq = lane >> 4;
#pragma unroll
  for (int ks = 0; ks < 2; ++ks) {
    int kun = ks * 4 + kq;
    bf16x8 a[8];
#pragma unroll
    for (int rg = 0; rg < 8; ++rg) {
      int row = wr * 128 + rg * 16 + r16;
      a[rg] = *(const bf16x8*)(A_lds + row * 128 + ((kun ^ (row & 7)) << 4));
    }
#pragma unroll
    for (int cg = 0; cg < 4; ++cg) {
      int n = wc * 64 + cg * 16 + r16;
      bf16x8 bfr = *(const bf16x8*)(W_lds + n * 128 + ((kun ^ (n & 7)) << 4));
#pragma unroll
      for (int rg = 0; rg < 8; ++rg)
        acc[rg][cg] = __builtin_amdgcn_mfma_f32_16x16x32_bf16(a[rg], bfr, acc[rg][cg], 0, 0, 0);
    }
  }
}

DEVI void stage_w(const unsigned short* __restrict__ wpt, char* W_lds, int k0,
                  int w, int lane) {
#pragma unroll
  for (int sI = 0; sI < 4; ++sI) {
    int g = w * 256 + sI * 64 + lane;   // 0..2047 : n = g>>3, unit u = g&7
    int n = g >> 3, u = g & 7;
    size_t gb = (size_t)n * (KTOT * 2) + (size_t)((k0 + ((u ^ (n & 7)) << 3)) * 2);
    __builtin_amdgcn_global_load_lds((const glb_u32_t*)((const char*)wpt + gb),
                                     (lds_u32_t*)(W_lds + g * 16), 16, 0, 0);
  }
}

__global__ __launch_bounds__(512) void k_main(const float* __restrict__ inp1,
                                              const float* __restrict__ inp2,
                                              const unsigned short* __restrict__ wpt,
                                              float* __restrict__ hf) {
  __shared__ u32x4 smem[8192];                    // 128 KiB: 2 x (A 32K + W 32K)
  char* base = (char*)smem;

  int lin = blockIdx.x;                           // 0..255
  int xcd = lin & 7, slot = lin >> 3;
  int c = xcd + ((slot >> 4) << 3);               // i-chunk 0..15 (XCD-pinned)
  int bblk = slot & 15;
  int b0 = bblk * 256;
  int i0 = c * 16;

  int t = threadIdx.x;
  int lane = t & 63, w = t >> 6;
  int wr = w >> 2, wc = w & 3;                    // 2 x 4 waves, tile 128 x 64

  int row_a = t >> 1;                             // builder row 0..255
  int ub = (t & 1) * 4;                           // builder unit base

  const float* inp1_row = inp1 + (size_t)(b0 + row_a) * 256;
  const float* inp2_row = inp2 + (size_t)(b0 + row_a) * 256;

  // prefetch this chunk's 16 inp1 scalars
  float s1[16];
  {
    const f32x4* p = (const f32x4*)(inp1_row + i0);
#pragma unroll
    for (int q = 0; q < 4; ++q) {
      f32x4 x = p[q];
#pragma unroll
      for (int e = 0; e < 4; ++e) s1[q * 4 + e] = x[e];
    }
  }

  float v[32];
  auto loadv = [&](int js) {
    const f32x4* p = (const f32x4*)(inp2_row + js * 64 + ub * 8);
#pragma unroll
    for (int q = 0; q < 8; ++q) {
      f32x4 x = p[q];
#pragma unroll
      for (int e = 0; e < 4; ++e) v[q * 4 + e] = x[e];
    }
  };

  auto build_main = [&](char* A_lds, int ii) {
    float s = s1[ii];
#pragma unroll
    for (int uu = 0; uu < 4; ++uu) {
      int u = ub + uu;
      u32x4 pk;
#pragma unroll
      for (int m = 0; m < 4; ++m)
        pk[m] = pack2(v[uu * 8 + 2 * m] * s, v[uu * 8 + 2 * m + 1] * s);
      *(u32x4*)(A_lds + row_a * 128 + ((u ^ (row_a & 7)) << 4)) = pk;
    }
  };

  auto build_tail = [&](char* A_lds) {
#pragma unroll
    for (int uu = 0; uu < 4; ++uu) {
      int u = ub + uu;
      int koff = (c - 8) * 64 + u * 8;            // 0..511
      const float* src = (koff < 256) ? (inp1_row + koff) : (inp2_row + (koff - 256));
      f32x4 x0 = *(const f32x4*)src;
      f32x4 x1 = *(const f32x4*)(src + 4);
      u32x4 pk;
      pk[0] = pack2(x0[0], x0[1]);
      pk[1] = pack2(x0[2], x0[3]);
      pk[2] = pack2(x1[0], x1[1]);
      pk[3] = pack2(x1[2], x1[3]);
      *(u32x4*)(A_lds + row_a * 128 + ((u ^ (row_a & 7)) << 4)) = pk;
    }
  };

  f32x4 acc[8][4] = {};

  const int NS = 64 + (c >= 8 ? 1 : 0);           // tail: k' = 65536 + (c-8)*64

  // prologue: stage step 0 into buffer 0
  loadv(0);
  stage_w(wpt, base + 32768, i0 * 256, w, lane);
  build_main(base, 0);
  __syncthreads();

  for (int s = 0; s < NS; ++s) {
    int cur = s & 1, nxt = cur ^ 1;
    char* A_cur = base + cur * 65536;
    char* W_cur = A_cur + 32768;
    char* A_nxt = base + nxt * 65536;
    char* W_nxt = A_nxt + 32768;

    int sn = s + 1;
    if (sn < NS) {
      if (sn < 64) {
        int js = sn >> 4, ii = sn & 15;
        stage_w(wpt, W_nxt, (i0 + ii) * 256 + js * 64, w, lane);
        if ((sn & 15) == 0) loadv(js);
        build_main(A_nxt, ii);
      } else {
        stage_w(wpt, W_nxt, 65536 + (c - 8) * 64, w, lane);
        build_tail(A_nxt);
      }
    }

    mfma_tiles(A_cur, W_cur, acc, lane, wr, wc);
    __syncthreads();
  }

  // epilogue: fp32 atomic accumulate (split-K over 16 chunks)
#pragma unroll
  for (int rg = 0; rg < 8; ++rg)
#pragma unroll
    for (int cg = 0; cg < 4; ++cg) {
      int n = wc * 64 + cg * 16 + (lane & 15);
      int brow = b0 + wr * 128 + rg * 16 + (lane >> 4) * 4;
#pragma unroll
      for (int r = 0; r < 4; ++r)
        atomicAdd(hf + (size_t)(brow + r) * 256 + n, acc[rg][cg][r]);
    }
}

// =====================================================================
// K4: out = relu( relu(hf + b1) @ W2 + b2 )  — finalize fused into GEMM2.
// =====================================================================
__global__ __launch_bounds__(256) void k_gemm2(const float* __restrict__ hf,
                                               const float* __restrict__ b1p,
                                               const unsigned short* __restrict__ w2bt,
                                               const float* __restrict__ b2,
                                               float* __restrict__ out) {
  int b0 = blockIdx.x * 128, n0 = blockIdx.y * 128;
  int t = threadIdx.x, lane = t & 63, w = t >> 6;
  int wr = w >> 1, wc = w & 1;
  int r16 = lane & 15, k8 = (lane >> 4) * 8;
  f32x4 acc[4][4] = {};
  for (int ks = 0; ks < 8; ++ks) {
    int k = ks * 32 + k8;
    f32x4 bb0 = *(const f32x4*)(b1p + k);
    f32x4 bb1 = *(const f32x4*)(b1p + k + 4);
    bf16x8 a[4], bb[4];
#pragma unroll
    for (int rg = 0; rg < 4; ++rg) {
      int b_ = b0 + wr * 64 + rg * 16 + r16;
      f32x4 x0 = *(const f32x4*)(hf + (size_t)b_ * 256 + k);
      f32x4 x1 = *(const f32x4*)(hf + (size_t)b_ * 256 + k + 4);
      u32x4 pk;
#pragma unroll
      for (int m = 0; m < 2; ++m) {
        float e0 = x0[2 * m] + bb0[2 * m];     e0 = e0 > 0.f ? e0 : 0.f;
        float e1 = x0[2 * m + 1] + bb0[2 * m + 1]; e1 = e1 > 0.f ? e1 : 0.f;
        pk[m] = pack2(e0, e1);
      }
#pragma unroll
      for (int m = 0; m < 2; ++m) {
        float e0 = x1[2 * m] + bb1[2 * m];     e0 = e0 > 0.f ? e0 : 0.f;
        float e1 = x1[2 * m + 1] + bb1[2 * m + 1]; e1 = e1 > 0.f ? e1 : 0.f;
        pk[2 + m] = pack2(e0, e1);
      }
      a[rg] = *(bf16x8*)&pk;
    }
#pragma unroll
    for (int cg = 0; cg < 4; ++cg) {
      int n2 = n0 + wc * 64 + cg * 16 + r16;
      bb[cg] = *(const bf16x8*)(w2bt + (size_t)n2 * 256 + k);
    }
#pragma unroll
    for (int rg = 0; rg < 4; ++rg)
#pragma unroll
      for (int cg = 0; cg < 4; ++cg)
        acc[rg][cg] = __builtin_amdgcn_mfma_f32_16x16x32_bf16(a[rg], bb[cg], acc[rg][cg], 0, 0, 0);
  }
#pragma unroll
  for (int rg = 0; rg < 4; ++rg)
#pragma unroll
    for (int cg = 0; cg < 4; ++cg) {
      int n2 = n0 + wc * 64 + cg * 16 + r16;
      float bias = b2[n2];
      int brow = b0 + wr * 64 + rg * 16 + (lane >> 4) * 4;
#pragma unroll
      for (int r = 0; r < 4; ++r) {
        float val = acc[rg][cg][r] + bias;
        out[(size_t)(brow + r) * 256 + n2] = val > 0.f ? val : 0.f;
      }
    }
}

// =====================================================================
extern "C" void kernel_launch(void* const* d_in, const int* in_sizes, int n_in,
                              void* d_out, int out_size, void* d_ws, size_t ws_size,
                              hipStream_t stream) {
  const float* inp1 = (const float*)d_in[0];
  const float* inp2 = (const float*)d_in[1];
  const float* W1   = (const float*)d_in[2];
  const float* b1   = (const float*)d_in[3];
  const float* W2   = (const float*)d_in[4];
  const float* b2   = (const float*)d_in[5];
  float* out = (float*)d_out;

  char* ws = (char*)d_ws;
  unsigned short* wpt  = (unsigned short*)(ws + OFF_WPT);
  unsigned short* w2bt = (unsigned short*)(ws + OFF_W2BT);
  float* b1p = (float*)(ws + OFF_B1P);
  float* hf  = (float*)(ws + OFF_HF);

  hipMemsetAsync(hf, 0, 4194304, stream);
  k_repack<<<dim3(1032, 4), 256, 0, stream>>>(W1, wpt);
  k_misc<<<256, 256, 0, stream>>>(W1, b1, W2, w2bt, b1p);
  k_main<<<256, 512, 0, stream>>>(inp1, inp2, wpt, hf);
  k_gemm2<<<dim3(32, 2), 256, 0, stream>>>(hf, b1p, w2bt, b2, out);
}